// Round 9
// baseline (177.887 us; speedup 1.0000x reference)
//
#include <hip/hip_runtime.h>
#include <cstdint>
#include <cstddef>

#define N_NODES 50000
#define N_EDGES 640000
#define DF 128
#define SLOT 64            // fixed per-node edge slot (mean deg 12.8; P(deg>64)~3e-23)

#define SC_BLOCKS 2500     // scatter blocks, 256 edges each, 1 edge/thread
#define GEMMB 782          // gemm_pool units, 4 waves each (782*4*16 >= 50000 rows)
#define FRAG_BLOCKS 16     // Wn1/Wn2 fragment conversion (2*2048 frags / 256)

typedef __attribute__((ext_vector_type(8))) short bf16x8;
typedef __attribute__((ext_vector_type(4))) float f32x4;

__device__ inline unsigned short f2bf(float f) {            // RNE float->bf16
    unsigned int u = __float_as_uint(f);
    return (unsigned short)((u + 0x7fffu + ((u >> 16) & 1u)) >> 16);
}

// ================= D1: slot scatter || gemm_pool(fp32 feat) || Wn frags ======
// R8 post-mortem: gap model — ~9 µs per dispatch boundary x 4-5 dispatches
// dominates the K1/K2 "fat" I chased for 4 rounds. This round: 5 -> 3
// dispatches, PassB deleted via fixed-slot one-pass scatter:
//     c = atomicAdd(&cnt[d],1); edges[d*SLOT+c] = {src, w}
// (1 edge/thread — single short atomic chain, unlike R5's 4 serial chains).
// gemm_pool reads fp32 feat (in-register cvt, R6-verified), stages W_pool in
// LDS with the conflict-free 16 B/lane layout (R5's 128 B-stride bug fixed),
// and writes featb as a by-product (R5-verified) for D2's Wn1 half.
// blocks [0,2500):        scatter
// blocks [2500,3282):     gemm_pool: hb = bf16(feat @ Wp^T + b_pool), +featb
// blocks [3282,3298):     Wn1/Wn2 fragments (B-operand order for 16x16x32)
__global__ __launch_bounds__(256) void d1_scatter_gemm(
    const float* __restrict__ feat,
    const float* __restrict__ W_pool,
    const float* __restrict__ W_neigh,
    const float* __restrict__ b_pool,
    const int* __restrict__ src,
    const int* __restrict__ dst,
    const float* __restrict__ w,
    unsigned short* __restrict__ featb,
    unsigned short* __restrict__ hb,
    unsigned short* __restrict__ Wn1_f,
    unsigned short* __restrict__ Wn2_f,
    int* __restrict__ cnt,              // pre-zeroed via hipMemsetAsync
    uint2* __restrict__ edges)
{
    int bid = blockIdx.x;
    int t = threadIdx.x;
    if (bid < SC_BLOCKS) {
        int e = bid * 256 + t;
        int s = src[e], d = dst[e];
        float wv = w[e];
        int c = atomicAdd(&cnt[d], 1);
        if (c < SLOT) {
            uint2 r; r.x = (unsigned int)s; r.y = __float_as_uint(wv);
            edges[(size_t)d * SLOT + c] = r;
        }
    } else if (bid < SC_BLOCKS + GEMMB) {
        // ---- gemm_pool from fp32 feat, Wp staged once in LDS (linear) ----
        __shared__ __align__(16) unsigned short wsh[16384];   // 32 KB Wp frags
        #pragma unroll
        for (int k = 0; k < 8; ++k) {
            int r8 = k * 256 + t;             // 0..2047; 16 B/lane contiguous
            int L = r8 & 63, tt2 = (r8 >> 6) & 3, c = r8 >> 8;
            const float* srcp = W_pool + (c * 16 + (L & 15)) * 128
                                       + tt2 * 32 + (L >> 4) * 8;
            float4 a = ((const float4*)srcp)[0];
            float4 b = ((const float4*)srcp)[1];
            ushort4 lo, hi;
            lo.x = f2bf(a.x); lo.y = f2bf(a.y); lo.z = f2bf(a.z); lo.w = f2bf(a.w);
            hi.x = f2bf(b.x); hi.y = f2bf(b.y); hi.z = f2bf(b.z); hi.w = f2bf(b.w);
            ((ushort4*)(wsh + r8 * 8))[0] = lo;
            ((ushort4*)(wsh + r8 * 8))[1] = hi;
        }
        __syncthreads();

        int gwave = (bid - SC_BLOCKS) * 4 + (t >> 6);
        int m0 = gwave * 16;
        if (m0 < N_NODES) {
            int lane = t & 63;
            const int n = lane & 15, quad = lane >> 4;
            f32x4 acc[8];
            #pragma unroll
            for (int c = 0; c < 8; ++c) {
                float bv = b_pool[c * 16 + n];
                acc[c] = (f32x4){bv, bv, bv, bv};
            }
            const float* fp = feat + (size_t)(m0 + n) * DF + quad * 8;
            unsigned short* fbp = featb + (size_t)(m0 + n) * DF + quad * 8;
            #pragma unroll
            for (int tt = 0; tt < 4; ++tt) {
                float4 a = ((const float4*)(fp + tt * 32))[0];
                float4 b = ((const float4*)(fp + tt * 32))[1];
                union { bf16x8 v; ushort4 u4[2]; } af;
                af.u4[0].x = f2bf(a.x); af.u4[0].y = f2bf(a.y);
                af.u4[0].z = f2bf(a.z); af.u4[0].w = f2bf(a.w);
                af.u4[1].x = f2bf(b.x); af.u4[1].y = f2bf(b.y);
                af.u4[1].z = f2bf(b.z); af.u4[1].w = f2bf(b.w);
                *(bf16x8*)(fbp + tt * 32) = af.v;          // featb by-product
                #pragma unroll
                for (int c = 0; c < 8; ++c) {
                    bf16x8 bfv = *(const bf16x8*)(wsh + (size_t)((c * 4 + tt) * 64 + lane) * 8);
                    acc[c] = __builtin_amdgcn_mfma_f32_16x16x32_bf16(af.v, bfv, acc[c], 0, 0, 0);
                }
            }
            #pragma unroll
            for (int c = 0; c < 8; ++c)
                #pragma unroll
                for (int r = 0; r < 4; ++r)
                    hb[(size_t)(m0 + quad * 4 + r) * DF + c * 16 + n] = f2bf(acc[c][r]);
        }
    } else {
        int g = (bid - SC_BLOCKS - GEMMB) * 256 + t;   // < 4096
        int m = g >> 11;                 // 0: Wn1, 1: Wn2
        int r8 = g & 2047;               // (c*4+tt)*64 + L fragment id
        int L = r8 & 63, tt = (r8 >> 6) & 3, c = r8 >> 8;
        int o = c * 16 + (L & 15);
        int kb = tt * 32 + (L >> 4) * 8;
        const float* srcp = W_neigh + o * 256 + (m ? 128 : 0) + kb;
        unsigned short* dstp = m ? Wn2_f : Wn1_f;
        ushort4 lo, hi;
        float4 a = ((const float4*)srcp)[0];
        float4 b = ((const float4*)srcp)[1];
        lo.x = f2bf(a.x); lo.y = f2bf(a.y); lo.z = f2bf(a.z); lo.w = f2bf(a.w);
        hi.x = f2bf(b.x); hi.y = f2bf(b.y); hi.z = f2bf(b.z); hi.w = f2bf(b.w);
        ((ushort4*)(dstp + r8 * 8))[0] = lo;
        ((ushort4*)(dstp + r8 * 8))[1] = hi;
    }
}

// ========== D2: fused max-gather + output GEMM (R2-verified, 44.7 µs) =======
// block = 1024 thr = 16 waves = 16 nodes, ONE node per wave; 3125 blocks.
// Gather reads the node's contiguous slot region with the clamped 8-edge
// loop (R5-verified slot addressing). Waves 0-7 then compute one 16-col
// block each: featb@Wn1 before the barrier, nsh@Wn2 after (swizzled LDS).
__global__ __launch_bounds__(1024) void fused_max_out(
    const unsigned short* __restrict__ featb,
    const unsigned short* __restrict__ hb,
    const int* __restrict__ cnt,
    const uint2* __restrict__ edges,
    const unsigned short* __restrict__ Wn1_f,
    const unsigned short* __restrict__ Wn2_f,
    const float* __restrict__ bias,
    float* __restrict__ out)
{
    __shared__ __align__(16) unsigned short nsh[16 * DF];   // swizzled 16x128 bf16
    const int t = threadIdx.x;
    const int lane = t & 63;
    const int wid = t >> 6;          // 0..15 == row within tile
    const int m0 = blockIdx.x * 16;
    const int half = lane >> 5;      // 0: even edge of pair, 1: odd edge
    const int q = lane & 31;         // column quarter: cols 4q..4q+3

    const int node = __builtin_amdgcn_readfirstlane(m0 + wid);
    int dg = cnt[node]; if (dg > SLOT) dg = SLOT;
    int beg = node * SLOT, end = beg + dg;
    float4 mx = make_float4(-3.4e38f, -3.4e38f, -3.4e38f, -3.4e38f);

    for (int e = beg; e < end; e += 8) {
        int i1 = min(e + 1, end - 1);
        int i2 = min(e + 2, end - 1);
        int i3 = min(e + 3, end - 1);
        int i4 = min(e + 4, end - 1);
        int i5 = min(e + 5, end - 1);
        int i6 = min(e + 6, end - 1);
        int i7 = min(e + 7, end - 1);
        uint2 e0 = edges[e],  e1 = edges[i1], e2 = edges[i2], e3 = edges[i3];
        uint2 e4 = edges[i4], e5 = edges[i5], e6 = edges[i6], e7 = edges[i7];
        uint2 mA = half ? e1 : e0;
        uint2 mB = half ? e3 : e2;
        uint2 mC = half ? e5 : e4;
        uint2 mD = half ? e7 : e6;
        float wA = __uint_as_float(mA.y);
        float wB = __uint_as_float(mB.y);
        float wC = __uint_as_float(mC.y);
        float wD = __uint_as_float(mD.y);
        uint2 pA = *(const uint2*)(hb + (size_t)mA.x * DF + q * 4);
        uint2 pB = *(const uint2*)(hb + (size_t)mB.x * DF + q * 4);
        uint2 pC = *(const uint2*)(hb + (size_t)mC.x * DF + q * 4);
        uint2 pD = *(const uint2*)(hb + (size_t)mD.x * DF + q * 4);
        mx.x = fmaxf(mx.x, __uint_as_float(pA.x << 16)          * wA);
        mx.y = fmaxf(mx.y, __uint_as_float(pA.x & 0xffff0000u)  * wA);
        mx.z = fmaxf(mx.z, __uint_as_float(pA.y << 16)          * wA);
        mx.w = fmaxf(mx.w, __uint_as_float(pA.y & 0xffff0000u)  * wA);
        mx.x = fmaxf(mx.x, __uint_as_float(pB.x << 16)          * wB);
        mx.y = fmaxf(mx.y, __uint_as_float(pB.x & 0xffff0000u)  * wB);
        mx.z = fmaxf(mx.z, __uint_as_float(pB.y << 16)          * wB);
        mx.w = fmaxf(mx.w, __uint_as_float(pB.y & 0xffff0000u)  * wB);
        mx.x = fmaxf(mx.x, __uint_as_float(pC.x << 16)          * wC);
        mx.y = fmaxf(mx.y, __uint_as_float(pC.x & 0xffff0000u)  * wC);
        mx.z = fmaxf(mx.z, __uint_as_float(pC.y << 16)          * wC);
        mx.w = fmaxf(mx.w, __uint_as_float(pC.y & 0xffff0000u)  * wC);
        mx.x = fmaxf(mx.x, __uint_as_float(pD.x << 16)          * wD);
        mx.y = fmaxf(mx.y, __uint_as_float(pD.x & 0xffff0000u)  * wD);
        mx.z = fmaxf(mx.z, __uint_as_float(pD.y << 16)          * wD);
        mx.w = fmaxf(mx.w, __uint_as_float(pD.y & 0xffff0000u)  * wD);
    }

    float4 o;
    o.x = fmaxf(mx.x, __shfl_xor(mx.x, 32));
    o.y = fmaxf(mx.y, __shfl_xor(mx.y, 32));
    o.z = fmaxf(mx.z, __shfl_xor(mx.z, 32));
    o.w = fmaxf(mx.w, __shfl_xor(mx.w, 32));
    if (dg == 0) o = make_float4(0.f, 0.f, 0.f, 0.f);
    if (half == 0) {
        ushort4 ob;
        ob.x = f2bf(o.x); ob.y = f2bf(o.y); ob.z = f2bf(o.z); ob.w = f2bf(o.w);
        int boff = wid * 256 + ((q * 8) ^ ((wid & 7) << 4));   // 8B-aligned
        *(ushort4*)((char*)nsh + boff) = ob;
    }

    // -------- phase 2: waves 0-7 each compute one 16-col block --------------
    const int n = lane & 15, quad = lane >> 4;
    f32x4 acc;
    if (wid < 8) {
        const int c = wid;
        float bv = bias[c * 16 + n];
        acc = (f32x4){bv, bv, bv, bv};
        const unsigned short* a0 = featb + (size_t)(m0 + n) * DF + quad * 8;
        #pragma unroll
        for (int tt = 0; tt < 4; ++tt) {
            bf16x8 af = *(const bf16x8*)(a0 + tt * 32);
            bf16x8 bfv = *(const bf16x8*)(Wn1_f + (size_t)((c * 4 + tt) * 64 + lane) * 8);
            acc = __builtin_amdgcn_mfma_f32_16x16x32_bf16(af, bfv, acc, 0, 0, 0);
        }
    }

    __syncthreads();                     // nsh fully written by all waves
    if (wid >= 8) return;                // free slots; waves 0-7 finish tile

    const int c = wid;
    #pragma unroll
    for (int tt = 0; tt < 4; ++tt) {
        int boff = (quad * 16 + tt * 64) ^ ((n & 7) << 4);         // 16B-aligned
        bf16x8 af = *(const bf16x8*)((const char*)nsh + n * 256 + boff);
        bf16x8 bfv = *(const bf16x8*)(Wn2_f + (size_t)((c * 4 + tt) * 64 + lane) * 8);
        acc = __builtin_amdgcn_mfma_f32_16x16x32_bf16(af, bfv, acc, 0, 0, 0);
    }

    #pragma unroll
    for (int r = 0; r < 4; ++r)
        out[(size_t)(m0 + quad * 4 + r) * DF + c * 16 + n] = acc[r];
}

extern "C" void kernel_launch(void* const* d_in, const int* in_sizes, int n_in,
                              void* d_out, int out_size, void* d_ws, size_t ws_size,
                              hipStream_t stream) {
    const float* feat    = (const float*)d_in[0];
    const float* weight  = (const float*)d_in[1];
    const int*   src     = (const int*)d_in[2];
    const int*   dst     = (const int*)d_in[3];
    const float* W_pool  = (const float*)d_in[4];
    const float* b_pool  = (const float*)d_in[5];
    const float* W_neigh = (const float*)d_in[6];
    const float* b_neigh = (const float*)d_in[7];
    float* out = (float*)d_out;

    char* ws = (char*)d_ws;
    unsigned short* featb  = (unsigned short*)(ws);              // 12,800,000 B
    unsigned short* hb     = (unsigned short*)(ws + 12800000);   // 12,800,000 B
    unsigned short* Wn1_f  = (unsigned short*)(ws + 25600000);   // 32,768 B
    unsigned short* Wn2_f  = (unsigned short*)(ws + 25632768);   // 32,768 B
    int*   cnt       = (int*)  (ws + 25665536);                  // 200,000 B
    uint2* edges     = (uint2*)(ws + 25865536);                  // 25,600,000 B -> ~51.5 MB

    hipMemsetAsync(cnt, 0, N_NODES * sizeof(int), stream);

    // D1: slot scatter || gemm_pool (fp32 feat -> hb + featb) || Wn frags
    const int D1_BLOCKS = SC_BLOCKS + GEMMB + FRAG_BLOCKS;   // 3298
    d1_scatter_gemm<<<D1_BLOCKS, 256, 0, stream>>>(
        feat, W_pool, W_neigh, b_pool, src, dst, weight,
        featb, hb, Wn1_f, Wn2_f, cnt, edges);

    // D2: fused segment-max gather (1 node/wave) + output GEMM
    fused_max_out<<<N_NODES / 16, 1024, 0, stream>>>(
        featb, hb, cnt, edges, Wn1_f, Wn2_f, b_neigh, out);
}

// Round 11
// 163.336 us; speedup vs baseline: 1.0891x; 1.0891x over previous
//
#include <hip/hip_runtime.h>
#include <cstdint>
#include <cstddef>

#define N_NODES 50000
#define N_EDGES 640000
#define DF 128

#define NBUCK 196          // buckets of 256 nodes: bucket = dst >> 8
#define BCAP  6144         // staging capacity per bucket (mean 3265, +50 sigma)
#define ECAP  8192         // padded per-bucket edge region (6144 + 256*7 pad max)
#define PA_BLOCKS 250      // PassA blocks, 2560 edges each (250*2560 = 640000)
#define DUMMY_ROW 50000    // hb row filled with -3.39e38 (pad records point here)

typedef __attribute__((ext_vector_type(8))) short bf16x8;
typedef __attribute__((ext_vector_type(4))) float f32x4;

__device__ inline unsigned short f2bf(float f) {            // RNE float->bf16
    unsigned int u = __float_as_uint(f);
    return (unsigned short)((u + 0x7fffu + ((u >> 16) & 1u)) >> 16);
}

// ================= K1: PassA (coarse bucket sort) || setup ===================
// R4-VERBATIM (the only verified-at-baseline structure).
// blocks [0,250):        PassA — bin 2560 edges into 196 coarse buckets.
// blocks [250,6500):     featb = bf16(feat)
// blocks [6500,6524):    W fragments (B-operand order for 16x16x32 MFMA)
// block  6524:           hb[DUMMY_ROW] = bf16(-3.39e38) for pad records
#define NF4 (N_NODES * DF / 4)        // 1,600,000
#define NWG (3 * 2048)
__global__ __launch_bounds__(256) void k1_setup_bucket(
    const float* __restrict__ feat,
    const float* __restrict__ W_pool,
    const float* __restrict__ W_neigh,
    const int* __restrict__ src,
    const int* __restrict__ dst,
    const float* __restrict__ w,
    unsigned short* __restrict__ featb,
    unsigned short* __restrict__ hb,
    unsigned short* __restrict__ Wp_f,
    unsigned short* __restrict__ Wn1_f,
    unsigned short* __restrict__ Wn2_f,
    int* __restrict__ bucketcnt,        // pre-zeroed via hipMemsetAsync
    uint2* __restrict__ staging)
{
    int bid = blockIdx.x;
    int t = threadIdx.x;
    if (bid < PA_BLOCKS) {
        __shared__ int cnt[NBUCK];
        __shared__ int runbase[NBUCK];
        int base = bid * 2560;
        if (t < NBUCK) cnt[t] = 0;
        __syncthreads();
        uint2 rec[10];
        int bk[10];
        #pragma unroll
        for (int i = 0; i < 10; ++i) {
            int e = base + i * 256 + t;
            int s = src[e], d = dst[e];
            bk[i] = d >> 8;
            rec[i].x = (unsigned int)s | ((unsigned int)(d & 255) << 16);
            rec[i].y = __float_as_uint(w[e]);
            atomicAdd(&cnt[bk[i]], 1);
        }
        __syncthreads();
        if (t < NBUCK) {
            runbase[t] = atomicAdd(&bucketcnt[t], cnt[t]);
            cnt[t] = 0;                 // reuse as within-run cursor
        }
        __syncthreads();
        #pragma unroll
        for (int i = 0; i < 10; ++i) {
            int r = atomicAdd(&cnt[bk[i]], 1);
            int pos = runbase[bk[i]] + r;
            if (pos < BCAP) staging[bk[i] * BCAP + pos] = rec[i];
        }
    } else if (bid < 250 + NF4 / 256) {
        int idx = (bid - PA_BLOCKS) * 256 + t;
        float4 v = ((const float4*)feat)[idx];
        ushort4 o;
        o.x = f2bf(v.x); o.y = f2bf(v.y); o.z = f2bf(v.z); o.w = f2bf(v.w);
        ((ushort4*)featb)[idx] = o;
    } else if (bid < 250 + NF4 / 256 + NWG / 256) {
        int g = (bid - PA_BLOCKS - NF4 / 256) * 256 + t;   // < NWG
        int m = g >> 11;
        int r8 = g & 2047;          // (c*4+tt)*64 + L
        int L = r8 & 63, tt = (r8 >> 6) & 3, c = r8 >> 8;
        int o = c * 16 + (L & 15);
        int kb = tt * 32 + (L >> 4) * 8;
        const float* srcp;
        unsigned short* dstp;
        if (m == 0)      { srcp = W_pool  + o * 128 + kb;       dstp = Wp_f;  }
        else if (m == 1) { srcp = W_neigh + o * 256 + kb;       dstp = Wn1_f; }
        else             { srcp = W_neigh + o * 256 + 128 + kb; dstp = Wn2_f; }
        ushort4 lo, hi;
        float4 a = ((const float4*)srcp)[0];
        float4 b = ((const float4*)srcp)[1];
        lo.x = f2bf(a.x); lo.y = f2bf(a.y); lo.z = f2bf(a.z); lo.w = f2bf(a.w);
        hi.x = f2bf(b.x); hi.y = f2bf(b.y); hi.z = f2bf(b.z); hi.w = f2bf(b.w);
        ((ushort4*)(dstp + r8 * 8))[0] = lo;
        ((ushort4*)(dstp + r8 * 8))[1] = hi;
    } else {
        // dummy hb row: bf16 -3.39e38 — pad-record messages never win the max
        if (t < DF) hb[(size_t)DUMMY_ROW * DF + t] = 0xFF7Fu;
    }
}

// ================= K2: gemm_pool || PassB (per-bucket fine sort) =============
// R4-VERBATIM. blocks [0,196): gemm_pool. blocks [196,392): PassB padded.
#define GEMMB 196          // ceil(3125 waves / 16)
__global__ __launch_bounds__(1024) void k2_gemm_passb(
    const unsigned short* __restrict__ featb,
    const unsigned short* __restrict__ Wp_f,
    const float* __restrict__ b_pool,
    unsigned short* __restrict__ hb,
    const int* __restrict__ bucketcnt,
    const uint2* __restrict__ staging,
    int* __restrict__ offsets,
    int* __restrict__ nend,
    uint2* __restrict__ edges)
{
    int t = threadIdx.x;
    if (blockIdx.x < GEMMB) {
        int wave = blockIdx.x * 16 + (t >> 6);
        int lane = t & 63;
        int m0 = wave * 16;
        if (m0 >= N_NODES) return;          // no barriers on this path
        const int n = lane & 15, quad = lane >> 4;

        f32x4 acc[8];
        #pragma unroll
        for (int c = 0; c < 8; ++c) {
            float bv = b_pool[c * 16 + n];
            acc[c] = (f32x4){bv, bv, bv, bv};
        }
        const unsigned short* aptr = featb + (size_t)(m0 + n) * DF + quad * 8;
        #pragma unroll
        for (int tt = 0; tt < 4; ++tt) {
            bf16x8 af = *(const bf16x8*)(aptr + tt * 32);
            #pragma unroll
            for (int c = 0; c < 8; ++c) {
                bf16x8 bf = *(const bf16x8*)(Wp_f + (size_t)((c * 4 + tt) * 64 + lane) * 8);
                acc[c] = __builtin_amdgcn_mfma_f32_16x16x32_bf16(af, bf, acc[c], 0, 0, 0);
            }
        }
        #pragma unroll
        for (int c = 0; c < 8; ++c)
            #pragma unroll
            for (int r = 0; r < 4; ++r)
                hb[(size_t)(m0 + quad * 4 + r) * DF + c * 16 + n] = f2bf(acc[c][r]);
    } else {
        __shared__ int dcnt[256];       // per-node count, then global cursor
        __shared__ int sc[256];         // scan scratch (padded counts)
        int b = blockIdx.x - GEMMB;     // 0..195
        int cnt = bucketcnt[b];
        if (cnt > BCAP) cnt = BCAP;     // PassA dropped overflow records

        if (t < 256) dcnt[t] = 0;
        __syncthreads();

        // load my staged records, count per-node degrees
        uint2 rec[6];
        int nit = (cnt + 1023) >> 10;
        for (int i = 0; i < nit; ++i) {
            int idx = i * 1024 + t;
            if (idx < cnt) {
                rec[i] = staging[(size_t)b * BCAP + idx];
                atomicAdd(&dcnt[(rec[i].x >> 16) & 255], 1);
            }
        }
        __syncthreads();
        int mydeg = 0, mypad = 0;
        if (t < 256) {
            mydeg = dcnt[t];
            mypad = (mydeg + 7) & ~7;   // round segment up to multiple of 8
            sc[t] = mypad;
        }
        __syncthreads();
        #pragma unroll
        for (int off = 1; off < 256; off <<= 1) {
            int u = (t < 256 && t >= off) ? sc[t - off] : 0;
            __syncthreads();
            if (t < 256) sc[t] += u;
            __syncthreads();
        }
        if (t < 256) {
            int beg = b * ECAP + sc[t] - mypad;     // exclusive padded prefix
            int node = b * 256 + t;
            if (node < N_NODES) {
                offsets[node] = beg;
                nend[node] = beg + mypad;           // PADDED end — gather bound
            }
            dcnt[t] = beg;                          // repurpose: write cursor
            uint2 dmy; dmy.x = DUMMY_ROW; dmy.y = 0x3F800000u;   // w = 1.0
            for (int k = mydeg; k < mypad; ++k) edges[beg + k] = dmy;
        }
        __syncthreads();
        for (int i = 0; i < nit; ++i) {
            int idx = i * 1024 + t;
            if (idx < cnt) {
                int dl = (rec[i].x >> 16) & 255;
                int pos = atomicAdd(&dcnt[dl], 1);
                uint2 fin;
                fin.x = rec[i].x & 0xFFFFu;     // src
                fin.y = rec[i].y;               // w bits
                edges[pos] = fin;
            }
        }
    }
}

// ========== K3fused: max-gather + output GEMM (R2-verified structure) =======
// R2 measured this shape at 44.7 µs (Occ 63%). Only change vs R2: padded
// segments from R4's PassB (offsets/nend, pads -> DUMMY_ROW) — the gather
// loop loses all 7 min-clamps. 1 node/wave, 16 waves/block, 3125 blocks.
// Waves 0-7: featb@Wn1 BEFORE the barrier (absorbs gather imbalance),
// nsh@Wn2 after (XOR-swizzled LDS, both sides). Waves 8-15 exit early.
// Replaces K3+K4: deletes the neighb round-trip AND one dispatch boundary.
__global__ __launch_bounds__(1024) void fused_max_out(
    const unsigned short* __restrict__ featb,
    const unsigned short* __restrict__ hb,
    const int* __restrict__ offsets,
    const int* __restrict__ nend,
    const uint2* __restrict__ edges,
    const unsigned short* __restrict__ Wn1_f,
    const unsigned short* __restrict__ Wn2_f,
    const float* __restrict__ bias,
    float* __restrict__ out)
{
    __shared__ __align__(16) unsigned short nsh[16 * DF];   // swizzled 16x128 bf16
    const int t = threadIdx.x;
    const int lane = t & 63;
    const int wid = t >> 6;          // 0..15 == row within tile
    const int m0 = blockIdx.x * 16;
    const int half = lane >> 5;      // 0: even edge of pair, 1: odd edge
    const int q = lane & 31;         // column quarter: cols 4q..4q+3

    const int node = __builtin_amdgcn_readfirstlane(m0 + wid);
    int beg = offsets[node], end = nend[node];   // padded (multiple of 8)
    float4 mx = make_float4(-3.4e38f, -3.4e38f, -3.4e38f, -3.4e38f);

    for (int e = beg; e < end; e += 8) {
        uint2 e0 = edges[e],     e1 = edges[e + 1], e2 = edges[e + 2], e3 = edges[e + 3];
        uint2 e4 = edges[e + 4], e5 = edges[e + 5], e6 = edges[e + 6], e7 = edges[e + 7];
        uint2 mA = half ? e1 : e0;
        uint2 mB = half ? e3 : e2;
        uint2 mC = half ? e5 : e4;
        uint2 mD = half ? e7 : e6;
        float wA = __uint_as_float(mA.y);
        float wB = __uint_as_float(mB.y);
        float wC = __uint_as_float(mC.y);
        float wD = __uint_as_float(mD.y);
        uint2 pA = *(const uint2*)(hb + (size_t)mA.x * DF + q * 4);
        uint2 pB = *(const uint2*)(hb + (size_t)mB.x * DF + q * 4);
        uint2 pC = *(const uint2*)(hb + (size_t)mC.x * DF + q * 4);
        uint2 pD = *(const uint2*)(hb + (size_t)mD.x * DF + q * 4);
        mx.x = fmaxf(mx.x, __uint_as_float(pA.x << 16)          * wA);
        mx.y = fmaxf(mx.y, __uint_as_float(pA.x & 0xffff0000u)  * wA);
        mx.z = fmaxf(mx.z, __uint_as_float(pA.y << 16)          * wA);
        mx.w = fmaxf(mx.w, __uint_as_float(pA.y & 0xffff0000u)  * wA);
        mx.x = fmaxf(mx.x, __uint_as_float(pB.x << 16)          * wB);
        mx.y = fmaxf(mx.y, __uint_as_float(pB.x & 0xffff0000u)  * wB);
        mx.z = fmaxf(mx.z, __uint_as_float(pB.y << 16)          * wB);
        mx.w = fmaxf(mx.w, __uint_as_float(pB.y & 0xffff0000u)  * wB);
        mx.x = fmaxf(mx.x, __uint_as_float(pC.x << 16)          * wC);
        mx.y = fmaxf(mx.y, __uint_as_float(pC.x & 0xffff0000u)  * wC);
        mx.z = fmaxf(mx.z, __uint_as_float(pC.y << 16)          * wC);
        mx.w = fmaxf(mx.w, __uint_as_float(pC.y & 0xffff0000u)  * wC);
        mx.x = fmaxf(mx.x, __uint_as_float(pD.x << 16)          * wD);
        mx.y = fmaxf(mx.y, __uint_as_float(pD.x & 0xffff0000u)  * wD);
        mx.z = fmaxf(mx.z, __uint_as_float(pD.y << 16)          * wD);
        mx.w = fmaxf(mx.w, __uint_as_float(pD.y & 0xffff0000u)  * wD);
    }

    float4 o;
    o.x = fmaxf(mx.x, __shfl_xor(mx.x, 32));
    o.y = fmaxf(mx.y, __shfl_xor(mx.y, 32));
    o.z = fmaxf(mx.z, __shfl_xor(mx.z, 32));
    o.w = fmaxf(mx.w, __shfl_xor(mx.w, 32));
    if (beg == end) o = make_float4(0.f, 0.f, 0.f, 0.f);
    if (half == 0) {
        ushort4 ob;
        ob.x = f2bf(o.x); ob.y = f2bf(o.y); ob.z = f2bf(o.z); ob.w = f2bf(o.w);
        int boff = wid * 256 + ((q * 8) ^ ((wid & 7) << 4));   // 8B-aligned
        *(ushort4*)((char*)nsh + boff) = ob;
    }

    // -------- phase 2: waves 0-7 each compute one 16-col block --------------
    const int n = lane & 15, quad = lane >> 4;
    f32x4 acc;
    if (wid < 8) {
        const int c = wid;
        float bv = bias[c * 16 + n];
        acc = (f32x4){bv, bv, bv, bv};
        const unsigned short* a0 = featb + (size_t)(m0 + n) * DF + quad * 8;
        #pragma unroll
        for (int tt = 0; tt < 4; ++tt) {
            bf16x8 af = *(const bf16x8*)(a0 + tt * 32);
            bf16x8 bfv = *(const bf16x8*)(Wn1_f + (size_t)((c * 4 + tt) * 64 + lane) * 8);
            acc = __builtin_amdgcn_mfma_f32_16x16x32_bf16(af, bfv, acc, 0, 0, 0);
        }
    }

    __syncthreads();                     // nsh fully written by all waves
    if (wid >= 8) return;                // free slots; waves 0-7 finish tile

    const int c = wid;
    #pragma unroll
    for (int tt = 0; tt < 4; ++tt) {
        int boff = (quad * 16 + tt * 64) ^ ((n & 7) << 4);         // 16B-aligned
        bf16x8 af = *(const bf16x8*)((const char*)nsh + n * 256 + boff);
        bf16x8 bfv = *(const bf16x8*)(Wn2_f + (size_t)((c * 4 + tt) * 64 + lane) * 8);
        acc = __builtin_amdgcn_mfma_f32_16x16x32_bf16(af, bfv, acc, 0, 0, 0);
    }

    #pragma unroll
    for (int r = 0; r < 4; ++r)
        out[(size_t)(m0 + quad * 4 + r) * DF + c * 16 + n] = acc[r];
}

extern "C" void kernel_launch(void* const* d_in, const int* in_sizes, int n_in,
                              void* d_out, int out_size, void* d_ws, size_t ws_size,
                              hipStream_t stream) {
    const float* feat    = (const float*)d_in[0];
    const float* weight  = (const float*)d_in[1];
    const int*   src     = (const int*)d_in[2];
    const int*   dst     = (const int*)d_in[3];
    const float* W_pool  = (const float*)d_in[4];
    const float* b_pool  = (const float*)d_in[5];
    const float* W_neigh = (const float*)d_in[6];
    const float* b_neigh = (const float*)d_in[7];
    float* out = (float*)d_out;

    char* ws = (char*)d_ws;
    unsigned short* featb  = (unsigned short*)(ws);              // 12,800,000 B
    unsigned short* hb     = (unsigned short*)(ws + 12800000);   // 12,800,256 B (50001 rows)
    unsigned short* Wp_f   = (unsigned short*)(ws + 25600512);   // 32,768 B
    unsigned short* Wn1_f  = (unsigned short*)(ws + 25633280);   // 32,768 B
    unsigned short* Wn2_f  = (unsigned short*)(ws + 25666048);   // 32,768 B
    int*   offsets   = (int*)  (ws + 25698816);                  // 200,000 B
    int*   nend      = (int*)  (ws + 25898816);                  // 200,000 B
    int*   bucketcnt = (int*)  (ws + 26098816);                  // 1,024 B
    uint2* staging   = (uint2*)(ws + 26099840);                  // 9,633,792 B
    uint2* edges     = (uint2*)(ws + 35733632);                  // 12,845,056 B (196*8192*8)
    // neighb eliminated by fusion -> ~48.6 MB total

    hipMemsetAsync(bucketcnt, 0, 1024, stream);

    // K1: PassA || featb conversion || W fragments || dummy hb row
    const int K1_BLOCKS = PA_BLOCKS + NF4 / 256 + NWG / 256 + 1;   // 6525
    k1_setup_bucket<<<K1_BLOCKS, 256, 0, stream>>>(
        feat, W_pool, W_neigh, src, dst, weight,
        featb, hb, Wp_f, Wn1_f, Wn2_f, bucketcnt, staging);

    // K2: gemm_pool (hb) || PassB (padded per-bucket edges + offsets/nend)
    k2_gemm_passb<<<GEMMB + NBUCK, 1024, 0, stream>>>(
        featb, Wp_f, b_pool, hb, bucketcnt, staging, offsets, nend, edges);

    // K3fused: segment-max gather (1 node/wave, clamp-free) + output GEMM
    fused_max_out<<<N_NODES / 16, 1024, 0, stream>>>(
        featb, hb, offsets, nend, edges, Wn1_f, Wn2_f, b_neigh, out);
}